// Round 6
// baseline (396.761 us; speedup 1.0000x reference)
//
#include <hip/hip_runtime.h>
#include <hip/hip_bf16.h>
#include <cmath>

// Problem constants
#define BSZ      256
#define D_IN     2048
#define D_OUT    2048
#define MG       1024      // M_GROUPS
#define NC       8         // N_CELLS
#define TOTAL    8192      // MG*NC
#define KGRP     128       // K_GROUPS (top-k groups)

typedef short bf16x8 __attribute__((ext_vector_type(8)));
typedef float f32x4  __attribute__((ext_vector_type(4)));

// fp32 <-> bf16 helpers (round-to-nearest-even, bit ops, deterministic)
__device__ inline short f2bf(float f) {
    unsigned u = __float_as_uint(f);
    unsigned r = (u + 0x7fffu + ((u >> 16) & 1u)) >> 16;
    return (short)r;
}
__device__ inline float bf2f(short s) {
    return __uint_as_float(((unsigned)(unsigned short)s) << 16);
}

// ===========================================================================
// fp32 tiled GEMM (z_a producer — decision-grade accuracy — and fallback)
// ===========================================================================
#define TILE 64
#define BK   32

template <int MODE>
__global__ __launch_bounds__(256) void gemm_f32(
    const float* __restrict__ A, const float* __restrict__ B,
    const float* __restrict__ bias, const float* __restrict__ aux,
    float* __restrict__ C, int M, int N, int K)
{
    __shared__ float As[BK][TILE + 4];
    __shared__ float Bs[BK][TILE];

    const int tid = threadIdx.x;
    const int tx = tid & 15;
    const int ty = tid >> 4;
    const int n0 = blockIdx.x * TILE;
    const int m0 = blockIdx.y * TILE;

    float acc[4][4] = {};

    for (int k0 = 0; k0 < K; k0 += BK) {
        #pragma unroll
        for (int it = 0; it < 2; ++it) {
            int lin = tid + it * 256;
            int row = lin >> 3;
            int c4  = lin & 7;
            float4 a = *(const float4*)&A[(size_t)(m0 + row) * K + k0 + c4 * 4];
            As[c4 * 4 + 0][row] = a.x;
            As[c4 * 4 + 1][row] = a.y;
            As[c4 * 4 + 2][row] = a.z;
            As[c4 * 4 + 3][row] = a.w;
        }
        #pragma unroll
        for (int it = 0; it < 2; ++it) {
            int lin = tid + it * 256;
            int row = lin >> 4;
            int c4  = lin & 15;
            *(float4*)&Bs[row][c4 * 4] =
                *(const float4*)&B[(size_t)(k0 + row) * N + n0 + c4 * 4];
        }
        __syncthreads();

        #pragma unroll
        for (int k = 0; k < BK; ++k) {
            float4 av = *(const float4*)&As[k][ty * 4];
            float4 bv = *(const float4*)&Bs[k][tx * 4];
            float a_[4] = {av.x, av.y, av.z, av.w};
            float b_[4] = {bv.x, bv.y, bv.z, bv.w};
            #pragma unroll
            for (int i = 0; i < 4; ++i)
                #pragma unroll
                for (int j = 0; j < 4; ++j)
                    acc[i][j] = fmaf(a_[i], b_[j], acc[i][j]);
        }
        __syncthreads();
    }

    #pragma unroll
    for (int i = 0; i < 4; ++i) {
        int m = m0 + ty * 4 + i;
        int n = n0 + tx * 4;
        float4 out;
        float* o = (float*)&out;
        #pragma unroll
        for (int j = 0; j < 4; ++j) {
            float v = acc[i][j] + bias[n + j];
            if (MODE == 1) v = aux[(size_t)m * MG + ((n + j) >> 3)] + v;
            o[j] = v;
        }
        *(float4*)&C[(size_t)m * N + n] = out;
    }
}

__global__ __launch_bounds__(256) void block_min(
    const float* __restrict__ x, int n, float* __restrict__ out)
{
    __shared__ float red[256];
    float v = 3.402823466e+38f;
    for (int i = blockIdx.x * 256 + threadIdx.x; i < n; i += gridDim.x * 256)
        v = fminf(v, x[i]);
    red[threadIdx.x] = v;
    __syncthreads();
    for (int s = 128; s > 0; s >>= 1) {
        if (threadIdx.x < s)
            red[threadIdx.x] = fminf(red[threadIdx.x], red[threadIdx.x + s]);
        __syncthreads();
    }
    if (threadIdx.x == 0) out[blockIdx.x] = red[0];
}

__global__ __launch_bounds__(256) void row_kernel(
    const float* __restrict__ sigma, const float* __restrict__ phi,
    const float* __restrict__ psi, const float* __restrict__ minval,
    float* __restrict__ decode, float* __restrict__ xb_new,
    float* __restrict__ phi_new, float* __restrict__ psi_new)
{
    __shared__ unsigned long long keys[MG];
    __shared__ int acell[MG];
    __shared__ int win[MG];

    const int b = blockIdx.x;
    const int tid = threadIdx.x;
    const float smin = minval[0];
    const float* srow = sigma + (size_t)b * TOTAL;
    const float* prow = phi + (size_t)b * TOTAL;
    const float* qrow = psi + (size_t)b * TOTAL;

    for (int g = tid; g < MG; g += 256) {
        float best = -3.402823466e+38f;
        int bc = 0;
        #pragma unroll
        for (int c = 0; c < NC; ++c) {
            float s = srow[g * NC + c];
            float p = prow[g * NC + c];
            float pi = (1.0f - p) * ((s - smin) + 1.0f);
            if (pi > best) { best = pi; bc = c; }
        }
        unsigned int bits = __float_as_uint(best);
        unsigned int u = (bits & 0x80000000u) ? ~bits : (bits | 0x80000000u);
        keys[g] = ((unsigned long long)(~u) << 32) | (unsigned int)g;
        acell[g] = bc;
        win[g] = 0;
    }
    __syncthreads();

    for (int k = 2; k <= MG; k <<= 1) {
        for (int j = k >> 1; j > 0; j >>= 1) {
            for (int t = tid; t < MG; t += 256) {
                int ixj = t ^ j;
                if (ixj > t) {
                    unsigned long long a = keys[t], bb_ = keys[ixj];
                    bool asc = ((t & k) == 0);
                    if ((a > bb_) == asc) { keys[t] = bb_; keys[ixj] = a; }
                }
            }
            __syncthreads();
        }
    }
    if (tid < KGRP) {
        int g = (int)(keys[tid] & 0xFFFFFFFFu);
        win[g] = 1;
    }
    __syncthreads();

    for (int j = tid; j < TOTAL; j += 256) {
        int g = j >> 3, c = j & 7;
        float s = srow[j];
        float y = 0.0f;
        if (win[g] && acell[g] == c) y = tanhf(s);
        float pn = fmaxf(prow[j] * 0.5f, y);
        float qn = fmaxf(qrow[j] * 0.5f, y);
        phi_new[(size_t)b * TOTAL + j] = pn;
        psi_new[(size_t)b * TOTAL + j] = qn;
        xb_new[(size_t)b * TOTAL + j] = qn;
    }

    for (int g = tid; g < MG; g += 256) {
        float d = 0.0f;
        if (win[g]) d = fmaxf(0.0f, tanhf(srow[g * NC + acell[g]]));
        decode[(size_t)b * MG + g] = d;
    }
}

// ===========================================================================
// bf16x3 MFMA GEMM: part[kslice] = A[m-tile, kslice] @ B[kslice, n-tile]
// BM=128 (M-split 2), BN=128, BK=64; 4 waves in 2x2, wave tile 64x64.
// A-frags direct global->VGPR (L2/L3-hot). B double-buffered in LDS with
// reg-staged issue-early/write-late (T14); ONE barrier per K-step.
// 2 blocks/CU (LDS 64KB/block, launch_bounds(256,2)).
// ===========================================================================
__global__ __launch_bounds__(256) void convert_bf(
    const float* __restrict__ src, short* __restrict__ h, short* __restrict__ l,
    int nchunks)
{
    for (int t = blockIdx.x * 256 + threadIdx.x; t < nchunks; t += gridDim.x * 256) {
        size_t idx = (size_t)t * 8;
        float4 v0 = *(const float4*)&src[idx];
        float4 v1 = *(const float4*)&src[idx + 4];
        float vv[8] = {v0.x, v0.y, v0.z, v0.w, v1.x, v1.y, v1.z, v1.w};
        bf16x8 hv, lv;
        #pragma unroll
        for (int e = 0; e < 8; ++e) {
            short hh = f2bf(vv[e]);
            hv[e] = hh;
            lv[e] = f2bf(vv[e] - bf2f(hh));
        }
        *(bf16x8*)&h[idx] = hv;
        *(bf16x8*)&l[idx] = lv;
    }
}

template <int KD, int BSTRIDE, int KPER>
__global__ __launch_bounds__(256, 2) void gemm_mfma(
    const short* __restrict__ Ah_g, const short* __restrict__ Al_g,
    const float* __restrict__ Bg, float* __restrict__ part)
{
    // [buf][n][8 chunks of 8k], chunk pos = kc ^ (n&7)  (proven r3 swizzle)
    __shared__ short Bh[2][128 * 64];   // 32 KB
    __shared__ short Bl[2][128 * 64];   // 32 KB

    const int tid = threadIdx.x;
    const int l = tid & 63;
    const int w = tid >> 6;
    const int wr = w >> 1;              // wave row (0..1)
    const int wc = w & 1;               // wave col (0..1)
    const int n0 = blockIdx.x * 128;
    const int m0 = blockIdx.y * 128;
    const int k0 = blockIdx.z * KPER;
    constexpr int NSTEP = KPER / 64;

    const int kc = tid >> 5;            // B-stage k-chunk 0..7
    const int n4 = (tid & 31) * 4;      // B-stage n quad

    f32x4 acc[4][4] = {};
    float4 f[8];

    // prologue: issue step-0 B-tile loads
    #pragma unroll
    for (int it = 0; it < 8; ++it)
        f[it] = *(const float4*)&Bg[(size_t)(k0 + kc * 8 + it) * BSTRIDE + n0 + n4];

    for (int st = 0; st < NSTEP; ++st) {
        const int cur = st & 1;
        const int kw = k0 + st * 64;

        // write staged regs -> LDS buf[cur] (convert fp32 -> hi/lo)
        #pragma unroll
        for (int j = 0; j < 4; ++j) {
            bf16x8 hv, lv;
            #pragma unroll
            for (int it = 0; it < 8; ++it) {
                float v = ((const float*)&f[it])[j];
                short hh = f2bf(v);
                hv[it] = hh;
                lv[it] = f2bf(v - bf2f(hh));
            }
            int n = n4 + j;
            int off = n * 64 + ((kc ^ (n & 7)) * 8);
            *(bf16x8*)&Bh[cur][off] = hv;
            *(bf16x8*)&Bl[cur][off] = lv;
        }
        // issue next-step loads early (hide HBM under compute)
        if (st + 1 < NSTEP) {
            const int kn = kw + 64;
            #pragma unroll
            for (int it = 0; it < 8; ++it)
                f[it] = *(const float4*)&Bg[(size_t)(kn + kc * 8 + it) * BSTRIDE + n0 + n4];
        }
        __syncthreads();   // buf[cur] ready; single barrier per step (dbuf)

        // compute: A-frags direct from global planes; B-frags from LDS
        #pragma unroll
        for (int kk = 0; kk < 2; ++kk) {
            const int chunk = kk * 4 + (l >> 4);
            bf16x8 ah[4], al[4];
            #pragma unroll
            for (int mt = 0; mt < 4; ++mt) {
                int row = m0 + wr * 64 + mt * 16 + (l & 15);
                size_t g = (size_t)row * KD + kw + chunk * 8;
                ah[mt] = *(const bf16x8*)&Ah_g[g];
                al[mt] = *(const bf16x8*)&Al_g[g];
            }
            #pragma unroll
            for (int nt = 0; nt < 4; ++nt) {
                int n = wc * 64 + nt * 16 + (l & 15);
                int off = n * 64 + ((chunk ^ (n & 7)) * 8);
                bf16x8 bh = *(const bf16x8*)&Bh[cur][off];
                bf16x8 bl = *(const bf16x8*)&Bl[cur][off];
                #pragma unroll
                for (int mt = 0; mt < 4; ++mt) {
                    acc[mt][nt] = __builtin_amdgcn_mfma_f32_16x16x32_bf16(
                        ah[mt], bh, acc[mt][nt], 0, 0, 0);
                    acc[mt][nt] = __builtin_amdgcn_mfma_f32_16x16x32_bf16(
                        ah[mt], bl, acc[mt][nt], 0, 0, 0);
                    acc[mt][nt] = __builtin_amdgcn_mfma_f32_16x16x32_bf16(
                        al[mt], bh, acc[mt][nt], 0, 0, 0);
                }
            }
        }
        // no trailing barrier: next step writes the OTHER buffer, and a wave
        // can only be one (counted) barrier ahead of its siblings.
    }

    // Epilogue: D layout col = lane&15, row = (lane>>4)*4 + reg
    float* P = part + (size_t)blockIdx.z * BSZ * BSTRIDE;
    #pragma unroll
    for (int mt = 0; mt < 4; ++mt) {
        int m = m0 + wr * 64 + mt * 16 + (l >> 4) * 4;
        #pragma unroll
        for (int nt = 0; nt < 4; ++nt) {
            int n = n0 + wc * 64 + nt * 16 + (l & 15);
            #pragma unroll
            for (int r = 0; r < 4; ++r)
                P[(size_t)(m + r) * BSTRIDE + n] = acc[mt][nt][r];
        }
    }
}

// Partial reduce + bias (+ z_a repeat + global-min for MODE 1).
// `out` may alias part slice 0 (element-wise read-then-write) -> no __restrict__.
template <int NSL, int NDIM, int MODE, int STR4>
__global__ __launch_bounds__(256) void reduce_part(
    const float* part, const float* __restrict__ aux,
    const float* __restrict__ bias, float* out,
    float* __restrict__ bmin)
{
    __shared__ float red[256];
    int i = blockIdx.x * 256 + threadIdx.x;
    size_t b4 = (size_t)i * 4;
    float4 s = {0.f, 0.f, 0.f, 0.f};
    #pragma unroll
    for (int sl = 0; sl < NSL; ++sl) {
        float4 p = *(const float4*)&part[(size_t)sl * STR4 * 4 + b4];
        s.x += p.x; s.y += p.y; s.z += p.z; s.w += p.w;
    }
    int col = (int)(b4 & (NDIM - 1));
    float4 bv = *(const float4*)&bias[col];
    float az = 0.f;
    if (MODE == 1) {
        int m = (int)(b4 >> 13);
        az = aux[m * MG + (col >> 3)];
    }
    s.x += bv.x + az; s.y += bv.y + az; s.z += bv.z + az; s.w += bv.w + az;
    *(float4*)&out[b4] = s;

    if (MODE == 1) {
        float v = fminf(fminf(s.x, s.y), fminf(s.z, s.w));
        red[threadIdx.x] = v;
        __syncthreads();
        for (int st = 128; st > 0; st >>= 1) {
            if (threadIdx.x < st)
                red[threadIdx.x] = fminf(red[threadIdx.x], red[threadIdx.x + st]);
            __syncthreads();
        }
        if (threadIdx.x == 0) bmin[blockIdx.x] = red[0];
    }
}

// ---------------------------------------------------------------------------
extern "C" void kernel_launch(void* const* d_in, const int* in_sizes, int n_in,
                              void* d_out, int out_size, void* d_ws, size_t ws_size,
                              hipStream_t stream)
{
    const float* x_a = (const float*)d_in[0];
    const float* x_b = (const float*)d_in[1];
    const float* phi = (const float*)d_in[2];
    const float* psi = (const float*)d_in[3];
    const float* Wa  = (const float*)d_in[4];
    const float* ba  = (const float*)d_in[5];
    const float* Wb  = (const float*)d_in[6];
    const float* bb  = (const float*)d_in[7];
    const float* Wd  = (const float*)d_in[8];
    const float* bd  = (const float*)d_in[9];

    float* out = (float*)d_out;
    float* pred    = out;
    float* xb_new  = out + BSZ * D_OUT;
    float* phi_new = out + BSZ * D_OUT + BSZ * TOTAL;
    float* psi_new = out + BSZ * D_OUT + 2 * BSZ * TOTAL;

    float* ws = (float*)d_ws;
    dim3 blk(256);

    // Workspace layout (float offsets); all 16B-aligned.
    // sigma ALIASES part slice 0 (see reduce_part note).
    const size_t OFF_ZA     = 0;            // 262144
    const size_t OFF_DECODE = 262144;       // 262144
    const size_t OFF_BMIN   = 524288;       // 2048
    const size_t OFF_MINV   = 526336;       // 16
    const size_t OFF_XBH    = 526352;       // 1048576 (2M shorts)
    const size_t OFF_XBL    = 1574928;      // 1048576
    const size_t OFF_DECH   = 2623504;      // 131072 (256K shorts)
    const size_t OFF_DECL   = 2754576;      // 131072
    const size_t OFF_PART   = 2885648;      // 16777216 (tier1) / 8388608 (tier2)
    const size_t NEED1 = (OFF_PART + 16777216) * 4;   // ~78.7 MB
    const size_t NEED2 = (OFF_PART + 8388608) * 4;    // ~45.1 MB (proven fits)

    if (ws_size >= NEED2) {
        float* z_a    = ws + OFF_ZA;
        float* decode = ws + OFF_DECODE;
        float* bmin   = ws + OFF_BMIN;
        float* minv   = ws + OFF_MINV;
        short* xbh    = (short*)(ws + OFF_XBH);
        short* xbl    = (short*)(ws + OFF_XBL);
        short* dech   = (short*)(ws + OFF_DECH);
        short* decl   = (short*)(ws + OFF_DECL);
        float* part   = ws + OFF_PART;
        float* sigma  = part;                 // alias, slice 0

        // z_a = x_a @ Wa + ba  -- fp32 (decision-grade accuracy; feeds top-k)
        gemm_f32<0><<<dim3(MG / TILE, BSZ / TILE), blk, 0, stream>>>(
            x_a, Wa, ba, nullptr, z_a, BSZ, MG, D_IN);

        // sigma = repeat(z_a,8) + x_b @ Wb + bb  -- bf16x3 MFMA
        convert_bf<<<1024, blk, 0, stream>>>(x_b, xbh, xbl, BSZ * TOTAL / 8);
        if (ws_size >= NEED1) {
            gemm_mfma<TOTAL, TOTAL, 1024><<<dim3(TOTAL / 128, 2, 8), blk, 0, stream>>>(
                xbh, xbl, Wb, part);
            reduce_part<8, TOTAL, 1, 524288><<<2048, blk, 0, stream>>>(
                part, z_a, bb, sigma, bmin);
        } else {
            gemm_mfma<TOTAL, TOTAL, 2048><<<dim3(TOTAL / 128, 2, 4), blk, 0, stream>>>(
                xbh, xbl, Wb, part);
            reduce_part<4, TOTAL, 1, 524288><<<2048, blk, 0, stream>>>(
                part, z_a, bb, sigma, bmin);
        }
        block_min<<<1, blk, 0, stream>>>(bmin, 2048, minv);

        // masks, y, elementwise outputs, decode_in (consumes sigma)
        row_kernel<<<BSZ, blk, 0, stream>>>(
            sigma, phi, psi, minv, decode, xb_new, phi_new, psi_new);

        // pred = decode @ Wd + bd  -- bf16x3 MFMA (no decisions downstream)
        convert_bf<<<128, blk, 0, stream>>>(decode, dech, decl, BSZ * MG / 8);
        gemm_mfma<MG, D_OUT, 64><<<dim3(D_OUT / 128, 2, 16), blk, 0, stream>>>(
            dech, decl, Wd, part);
        reduce_part<16, D_OUT, 2, 131072><<<512, blk, 0, stream>>>(
            part, nullptr, bd, pred, nullptr);
    } else {
        // Fallback: proven fp32 path (needs ~10.5 MB ws)
        float* z_a    = ws;
        float* sigma  = ws + 262144;
        float* decode = ws + 262144 + 2097152;
        float* bmin   = ws + 2621440;
        float* minv   = ws + 2622464;

        gemm_f32<0><<<dim3(MG / TILE, BSZ / TILE), blk, 0, stream>>>(
            x_a, Wa, ba, nullptr, z_a, BSZ, MG, D_IN);
        gemm_f32<1><<<dim3(TOTAL / TILE, BSZ / TILE), blk, 0, stream>>>(
            x_b, Wb, bb, z_a, sigma, BSZ, TOTAL, TOTAL);
        block_min<<<1024, blk, 0, stream>>>(sigma, BSZ * TOTAL, bmin);
        block_min<<<1, blk, 0, stream>>>(bmin, 1024, minv);
        row_kernel<<<BSZ, blk, 0, stream>>>(
            sigma, phi, psi, minv, decode, xb_new, phi_new, psi_new);
        gemm_f32<0><<<dim3(D_OUT / TILE, BSZ / TILE), blk, 0, stream>>>(
            decode, Wd, bd, nullptr, pred, BSZ, D_OUT, MG);
    }
}

// Round 7
// 373.220 us; speedup vs baseline: 1.0631x; 1.0631x over previous
//
#include <hip/hip_runtime.h>
#include <hip/hip_bf16.h>
#include <cmath>

// Problem constants
#define BSZ      256
#define D_IN     2048
#define D_OUT    2048
#define MG       1024      // M_GROUPS
#define NC       8         // N_CELLS
#define TOTAL    8192      // MG*NC
#define KGRP     128       // K_GROUPS (top-k groups)

typedef short bf16x8 __attribute__((ext_vector_type(8)));
typedef float f32x4  __attribute__((ext_vector_type(4)));

// fp32 <-> bf16 helpers (round-to-nearest-even, bit ops, deterministic)
__device__ inline short f2bf(float f) {
    unsigned u = __float_as_uint(f);
    unsigned r = (u + 0x7fffu + ((u >> 16) & 1u)) >> 16;
    return (short)r;
}
__device__ inline float bf2f(short s) {
    return __uint_as_float(((unsigned)(unsigned short)s) << 16);
}

// ===========================================================================
// fp32 tiled GEMM (z_a producer — decision-grade accuracy — and fallback)
// ===========================================================================
#define TILE 64
#define BK   32

template <int MODE>
__global__ __launch_bounds__(256) void gemm_f32(
    const float* __restrict__ A, const float* __restrict__ B,
    const float* __restrict__ bias, const float* __restrict__ aux,
    float* __restrict__ C, int M, int N, int K)
{
    __shared__ float As[BK][TILE + 4];
    __shared__ float Bs[BK][TILE];

    const int tid = threadIdx.x;
    const int tx = tid & 15;
    const int ty = tid >> 4;
    const int n0 = blockIdx.x * TILE;
    const int m0 = blockIdx.y * TILE;

    float acc[4][4] = {};

    for (int k0 = 0; k0 < K; k0 += BK) {
        #pragma unroll
        for (int it = 0; it < 2; ++it) {
            int lin = tid + it * 256;
            int row = lin >> 3;
            int c4  = lin & 7;
            float4 a = *(const float4*)&A[(size_t)(m0 + row) * K + k0 + c4 * 4];
            As[c4 * 4 + 0][row] = a.x;
            As[c4 * 4 + 1][row] = a.y;
            As[c4 * 4 + 2][row] = a.z;
            As[c4 * 4 + 3][row] = a.w;
        }
        #pragma unroll
        for (int it = 0; it < 2; ++it) {
            int lin = tid + it * 256;
            int row = lin >> 4;
            int c4  = lin & 15;
            *(float4*)&Bs[row][c4 * 4] =
                *(const float4*)&B[(size_t)(k0 + row) * N + n0 + c4 * 4];
        }
        __syncthreads();

        #pragma unroll
        for (int k = 0; k < BK; ++k) {
            float4 av = *(const float4*)&As[k][ty * 4];
            float4 bv = *(const float4*)&Bs[k][tx * 4];
            float a_[4] = {av.x, av.y, av.z, av.w};
            float b_[4] = {bv.x, bv.y, bv.z, bv.w};
            #pragma unroll
            for (int i = 0; i < 4; ++i)
                #pragma unroll
                for (int j = 0; j < 4; ++j)
                    acc[i][j] = fmaf(a_[i], b_[j], acc[i][j]);
        }
        __syncthreads();
    }

    #pragma unroll
    for (int i = 0; i < 4; ++i) {
        int m = m0 + ty * 4 + i;
        int n = n0 + tx * 4;
        float4 out;
        float* o = (float*)&out;
        #pragma unroll
        for (int j = 0; j < 4; ++j) {
            float v = acc[i][j] + bias[n + j];
            if (MODE == 1) v = aux[(size_t)m * MG + ((n + j) >> 3)] + v;
            o[j] = v;
        }
        *(float4*)&C[(size_t)m * N + n] = out;
    }
}

__global__ __launch_bounds__(256) void block_min(
    const float* __restrict__ x, int n, float* __restrict__ out)
{
    __shared__ float red[256];
    float v = 3.402823466e+38f;
    for (int i = blockIdx.x * 256 + threadIdx.x; i < n; i += gridDim.x * 256)
        v = fminf(v, x[i]);
    red[threadIdx.x] = v;
    __syncthreads();
    for (int s = 128; s > 0; s >>= 1) {
        if (threadIdx.x < s)
            red[threadIdx.x] = fminf(red[threadIdx.x], red[threadIdx.x + s]);
        __syncthreads();
    }
    if (threadIdx.x == 0) out[blockIdx.x] = red[0];
}

__global__ __launch_bounds__(256) void row_kernel(
    const float* __restrict__ sigma, const float* __restrict__ phi,
    const float* __restrict__ psi, const float* __restrict__ minval,
    float* __restrict__ decode, float* __restrict__ xb_new,
    float* __restrict__ phi_new, float* __restrict__ psi_new)
{
    __shared__ unsigned long long keys[MG];
    __shared__ int acell[MG];
    __shared__ int win[MG];

    const int b = blockIdx.x;
    const int tid = threadIdx.x;
    const float smin = minval[0];
    const float* srow = sigma + (size_t)b * TOTAL;
    const float* prow = phi + (size_t)b * TOTAL;
    const float* qrow = psi + (size_t)b * TOTAL;

    for (int g = tid; g < MG; g += 256) {
        float best = -3.402823466e+38f;
        int bc = 0;
        #pragma unroll
        for (int c = 0; c < NC; ++c) {
            float s = srow[g * NC + c];
            float p = prow[g * NC + c];
            float pi = (1.0f - p) * ((s - smin) + 1.0f);
            if (pi > best) { best = pi; bc = c; }
        }
        unsigned int bits = __float_as_uint(best);
        unsigned int u = (bits & 0x80000000u) ? ~bits : (bits | 0x80000000u);
        keys[g] = ((unsigned long long)(~u) << 32) | (unsigned int)g;
        acell[g] = bc;
        win[g] = 0;
    }
    __syncthreads();

    for (int k = 2; k <= MG; k <<= 1) {
        for (int j = k >> 1; j > 0; j >>= 1) {
            for (int t = tid; t < MG; t += 256) {
                int ixj = t ^ j;
                if (ixj > t) {
                    unsigned long long a = keys[t], bb_ = keys[ixj];
                    bool asc = ((t & k) == 0);
                    if ((a > bb_) == asc) { keys[t] = bb_; keys[ixj] = a; }
                }
            }
            __syncthreads();
        }
    }
    if (tid < KGRP) {
        int g = (int)(keys[tid] & 0xFFFFFFFFu);
        win[g] = 1;
    }
    __syncthreads();

    for (int j = tid; j < TOTAL; j += 256) {
        int g = j >> 3, c = j & 7;
        float s = srow[j];
        float y = 0.0f;
        if (win[g] && acell[g] == c) y = tanhf(s);
        float pn = fmaxf(prow[j] * 0.5f, y);
        float qn = fmaxf(qrow[j] * 0.5f, y);
        phi_new[(size_t)b * TOTAL + j] = pn;
        psi_new[(size_t)b * TOTAL + j] = qn;
        xb_new[(size_t)b * TOTAL + j] = qn;
    }

    for (int g = tid; g < MG; g += 256) {
        float d = 0.0f;
        if (win[g]) d = fmaxf(0.0f, tanhf(srow[g * NC + acell[g]]));
        decode[(size_t)b * MG + g] = d;
    }
}

// ===========================================================================
// bf16x3 MFMA GEMM: part[kslice] = A[m-tile, kslice] @ B[kslice, n-tile]
// BM=128, BN=256, BK=64. 512 threads = 8 waves (4 wave-rows x 2 wave-cols),
// wave tile 32x128, acc[2][8]. A-frags direct global->VGPR (each A element
// read once per block; BN=256 halves chip A-traffic vs BN=128). B dbuf in
// LDS (128 KB), reg-staged issue-early/write-late, ONE barrier per step.
// Staging map kc=tid&7 makes ds_write_b128 conflict-free (8-cyc minimum).
// ===========================================================================
__global__ __launch_bounds__(256) void convert_bf(
    const float* __restrict__ src, short* __restrict__ h, short* __restrict__ l,
    int nchunks)
{
    for (int t = blockIdx.x * 256 + threadIdx.x; t < nchunks; t += gridDim.x * 256) {
        size_t idx = (size_t)t * 8;
        float4 v0 = *(const float4*)&src[idx];
        float4 v1 = *(const float4*)&src[idx + 4];
        float vv[8] = {v0.x, v0.y, v0.z, v0.w, v1.x, v1.y, v1.z, v1.w};
        bf16x8 hv, lv;
        #pragma unroll
        for (int e = 0; e < 8; ++e) {
            short hh = f2bf(vv[e]);
            hv[e] = hh;
            lv[e] = f2bf(vv[e] - bf2f(hh));
        }
        *(bf16x8*)&h[idx] = hv;
        *(bf16x8*)&l[idx] = lv;
    }
}

template <int KD, int BSTRIDE, int KPER>
__global__ __launch_bounds__(512, 2) void gemm_mfma(
    const short* __restrict__ Ah_g, const short* __restrict__ Al_g,
    const float* __restrict__ Bg, float* __restrict__ part)
{
    // [buf][n][8 chunks of 8k], chunk pos = kc ^ (n&7)  (proven r3 swizzle)
    __shared__ short Bh[2][256 * 64];   // 64 KB
    __shared__ short Bl[2][256 * 64];   // 64 KB

    const int tid = threadIdx.x;
    const int l = tid & 63;
    const int w = tid >> 6;
    const int wr = w >> 1;              // wave row (0..3), 32 rows each
    const int wc = w & 1;               // wave col (0..1), 128 cols each
    const int n0 = blockIdx.x * 256;
    const int m0 = blockIdx.y * 128;
    const int k0 = blockIdx.z * KPER;
    constexpr int NSTEP = KPER / 64;

    const int kc = tid & 7;             // B-stage k-chunk (per-lane -> spreads banks)
    const int n4 = (tid >> 3) * 4;      // B-stage n quad (0..252)

    f32x4 acc[2][8] = {};
    float4 f[8];

    // prologue: issue step-0 B-tile loads
    #pragma unroll
    for (int it = 0; it < 8; ++it)
        f[it] = *(const float4*)&Bg[(size_t)(k0 + kc * 8 + it) * BSTRIDE + n0 + n4];

    for (int st = 0; st < NSTEP; ++st) {
        const int cur = st & 1;
        const int kw = k0 + st * 64;

        // write staged regs -> LDS buf[cur] (convert fp32 -> hi/lo)
        #pragma unroll
        for (int j = 0; j < 4; ++j) {
            bf16x8 hv, lv;
            #pragma unroll
            for (int it = 0; it < 8; ++it) {
                float v = ((const float*)&f[it])[j];
                short hh = f2bf(v);
                hv[it] = hh;
                lv[it] = f2bf(v - bf2f(hh));
            }
            int n = n4 + j;
            int off = n * 64 + ((kc ^ (n & 7)) * 8);
            *(bf16x8*)&Bh[cur][off] = hv;
            *(bf16x8*)&Bl[cur][off] = lv;
        }
        // issue next-step loads early (hide HBM under compute)
        if (st + 1 < NSTEP) {
            const int kn = kw + 64;
            #pragma unroll
            for (int it = 0; it < 8; ++it)
                f[it] = *(const float4*)&Bg[(size_t)(kn + kc * 8 + it) * BSTRIDE + n0 + n4];
        }
        __syncthreads();   // buf[cur] ready; single barrier per step (dbuf)

        // compute: A-frags direct from global planes; B-frags from LDS
        #pragma unroll
        for (int kk = 0; kk < 2; ++kk) {
            const int chunk = kk * 4 + (l >> 4);
            bf16x8 ah[2], al[2];
            #pragma unroll
            for (int mt = 0; mt < 2; ++mt) {
                int row = m0 + wr * 32 + mt * 16 + (l & 15);
                size_t g = (size_t)row * KD + kw + chunk * 8;
                ah[mt] = *(const bf16x8*)&Ah_g[g];
                al[mt] = *(const bf16x8*)&Al_g[g];
            }
            #pragma unroll
            for (int nt = 0; nt < 8; ++nt) {
                int n = wc * 128 + nt * 16 + (l & 15);
                int off = n * 64 + ((chunk ^ (n & 7)) * 8);
                bf16x8 bh = *(const bf16x8*)&Bh[cur][off];
                bf16x8 bl = *(const bf16x8*)&Bl[cur][off];
                #pragma unroll
                for (int mt = 0; mt < 2; ++mt) {
                    acc[mt][nt] = __builtin_amdgcn_mfma_f32_16x16x32_bf16(
                        ah[mt], bh, acc[mt][nt], 0, 0, 0);
                    acc[mt][nt] = __builtin_amdgcn_mfma_f32_16x16x32_bf16(
                        ah[mt], bl, acc[mt][nt], 0, 0, 0);
                    acc[mt][nt] = __builtin_amdgcn_mfma_f32_16x16x32_bf16(
                        al[mt], bh, acc[mt][nt], 0, 0, 0);
                }
            }
        }
        // no trailing barrier: next step writes the OTHER buffer, and a wave
        // can only be one barrier ahead of its siblings.
    }

    // Epilogue: D layout col = lane&15, row = (lane>>4)*4 + reg
    float* P = part + (size_t)blockIdx.z * BSZ * BSTRIDE;
    #pragma unroll
    for (int mt = 0; mt < 2; ++mt) {
        int m = m0 + wr * 32 + mt * 16 + (l >> 4) * 4;
        #pragma unroll
        for (int nt = 0; nt < 8; ++nt) {
            int n = n0 + wc * 128 + nt * 16 + (l & 15);
            #pragma unroll
            for (int r = 0; r < 4; ++r)
                P[(size_t)(m + r) * BSTRIDE + n] = acc[mt][nt][r];
        }
    }
}

// Partial reduce + bias (+ z_a repeat + global-min for MODE 1).
// `out` may alias part slice 0 (element-wise read-then-write) -> no __restrict__.
template <int NSL, int NDIM, int MODE, int STR4>
__global__ __launch_bounds__(256) void reduce_part(
    const float* part, const float* __restrict__ aux,
    const float* __restrict__ bias, float* out,
    float* __restrict__ bmin)
{
    __shared__ float red[256];
    int i = blockIdx.x * 256 + threadIdx.x;
    size_t b4 = (size_t)i * 4;
    float4 s = {0.f, 0.f, 0.f, 0.f};
    #pragma unroll
    for (int sl = 0; sl < NSL; ++sl) {
        float4 p = *(const float4*)&part[(size_t)sl * STR4 * 4 + b4];
        s.x += p.x; s.y += p.y; s.z += p.z; s.w += p.w;
    }
    int col = (int)(b4 & (NDIM - 1));
    float4 bv = *(const float4*)&bias[col];
    float az = 0.f;
    if (MODE == 1) {
        int m = (int)(b4 >> 13);
        az = aux[m * MG + (col >> 3)];
    }
    s.x += bv.x + az; s.y += bv.y + az; s.z += bv.z + az; s.w += bv.w + az;
    *(float4*)&out[b4] = s;

    if (MODE == 1) {
        float v = fminf(fminf(s.x, s.y), fminf(s.z, s.w));
        red[threadIdx.x] = v;
        __syncthreads();
        for (int st = 128; st > 0; st >>= 1) {
            if (threadIdx.x < st)
                red[threadIdx.x] = fminf(red[threadIdx.x], red[threadIdx.x + st]);
            __syncthreads();
        }
        if (threadIdx.x == 0) bmin[blockIdx.x] = red[0];
    }
}

// ---------------------------------------------------------------------------
extern "C" void kernel_launch(void* const* d_in, const int* in_sizes, int n_in,
                              void* d_out, int out_size, void* d_ws, size_t ws_size,
                              hipStream_t stream)
{
    const float* x_a = (const float*)d_in[0];
    const float* x_b = (const float*)d_in[1];
    const float* phi = (const float*)d_in[2];
    const float* psi = (const float*)d_in[3];
    const float* Wa  = (const float*)d_in[4];
    const float* ba  = (const float*)d_in[5];
    const float* Wb  = (const float*)d_in[6];
    const float* bb  = (const float*)d_in[7];
    const float* Wd  = (const float*)d_in[8];
    const float* bd  = (const float*)d_in[9];

    float* out = (float*)d_out;
    float* pred    = out;
    float* xb_new  = out + BSZ * D_OUT;
    float* phi_new = out + BSZ * D_OUT + BSZ * TOTAL;
    float* psi_new = out + BSZ * D_OUT + 2 * BSZ * TOTAL;

    float* ws = (float*)d_ws;
    dim3 blk(256);
    dim3 blk512(512);

    // Workspace layout (float offsets); all 16B-aligned.
    // sigma ALIASES part slice 0 (see reduce_part note).
    const size_t OFF_ZA     = 0;            // 262144
    const size_t OFF_DECODE = 262144;       // 262144
    const size_t OFF_BMIN   = 524288;       // 2048
    const size_t OFF_MINV   = 526336;       // 16
    const size_t OFF_XBH    = 526352;       // 1048576 (2M shorts)
    const size_t OFF_XBL    = 1574928;      // 1048576
    const size_t OFF_DECH   = 2623504;      // 131072 (256K shorts)
    const size_t OFF_DECL   = 2754576;      // 131072
    const size_t OFF_PART   = 2885648;      // 8388608 floats (32 MB)
    const size_t NEED = (OFF_PART + 8388608) * 4;    // ~45.1 MB (proven fits)

    if (ws_size >= NEED) {
        float* z_a    = ws + OFF_ZA;
        float* decode = ws + OFF_DECODE;
        float* bmin   = ws + OFF_BMIN;
        float* minv   = ws + OFF_MINV;
        short* xbh    = (short*)(ws + OFF_XBH);
        short* xbl    = (short*)(ws + OFF_XBL);
        short* dech   = (short*)(ws + OFF_DECH);
        short* decl   = (short*)(ws + OFF_DECL);
        float* part   = ws + OFF_PART;
        float* sigma  = part;                 // alias, slice 0

        // z_a = x_a @ Wa + ba  -- fp32 (decision-grade accuracy; feeds top-k)
        gemm_f32<0><<<dim3(MG / TILE, BSZ / TILE), blk, 0, stream>>>(
            x_a, Wa, ba, nullptr, z_a, BSZ, MG, D_IN);

        // sigma = repeat(z_a,8) + x_b @ Wb + bb  -- bf16x3 MFMA
        convert_bf<<<1024, blk, 0, stream>>>(x_b, xbh, xbl, BSZ * TOTAL / 8);
        gemm_mfma<TOTAL, TOTAL, 2048><<<dim3(TOTAL / 256, 2, 4), blk512, 0, stream>>>(
            xbh, xbl, Wb, part);
        reduce_part<4, TOTAL, 1, 524288><<<2048, blk, 0, stream>>>(
            part, z_a, bb, sigma, bmin);
        block_min<<<1, blk, 0, stream>>>(bmin, 2048, minv);

        // masks, y, elementwise outputs, decode_in (consumes sigma)
        row_kernel<<<BSZ, blk, 0, stream>>>(
            sigma, phi, psi, minv, decode, xb_new, phi_new, psi_new);

        // pred = decode @ Wd + bd  -- bf16x3 MFMA (no decisions downstream)
        convert_bf<<<128, blk, 0, stream>>>(decode, dech, decl, BSZ * MG / 8);
        gemm_mfma<MG, D_OUT, 64><<<dim3(D_OUT / 256, 2, 16), blk512, 0, stream>>>(
            dech, decl, Wd, part);
        reduce_part<16, D_OUT, 2, 131072><<<512, blk, 0, stream>>>(
            part, nullptr, bd, pred, nullptr);
    } else {
        // Fallback: proven fp32 path (needs ~10.5 MB ws)
        float* z_a    = ws;
        float* sigma  = ws + 262144;
        float* decode = ws + 262144 + 2097152;
        float* bmin   = ws + 2621440;
        float* minv   = ws + 2622464;

        gemm_f32<0><<<dim3(MG / TILE, BSZ / TILE), blk, 0, stream>>>(
            x_a, Wa, ba, nullptr, z_a, BSZ, MG, D_IN);
        gemm_f32<1><<<dim3(TOTAL / TILE, BSZ / TILE), blk, 0, stream>>>(
            x_b, Wb, bb, z_a, sigma, BSZ, TOTAL, TOTAL);
        block_min<<<1024, blk, 0, stream>>>(sigma, BSZ * TOTAL, bmin);
        block_min<<<1, blk, 0, stream>>>(bmin, 1024, minv);
        row_kernel<<<BSZ, blk, 0, stream>>>(
            sigma, phi, psi, minv, decode, xb_new, phi_new, psi_new);
        gemm_f32<0><<<dim3(D_OUT / TILE, BSZ / TILE), blk, 0, stream>>>(
            decode, Wd, bd, nullptr, pred, BSZ, D_OUT, MG);
    }
}

// Round 8
// 369.769 us; speedup vs baseline: 1.0730x; 1.0093x over previous
//
#include <hip/hip_runtime.h>
#include <hip/hip_bf16.h>
#include <cmath>

// Problem constants
#define BSZ      256
#define D_IN     2048
#define D_OUT    2048
#define MG       1024      // M_GROUPS
#define NC       8         // N_CELLS
#define TOTAL    8192      // MG*NC
#define KGRP     128       // K_GROUPS (top-k groups)

typedef short bf16x8 __attribute__((ext_vector_type(8)));
typedef float f32x4  __attribute__((ext_vector_type(4)));

// fp32 <-> bf16 helpers (round-to-nearest-even, bit ops, deterministic)
__device__ inline short f2bf(float f) {
    unsigned u = __float_as_uint(f);
    unsigned r = (u + 0x7fffu + ((u >> 16) & 1u)) >> 16;
    return (short)r;
}
__device__ inline float bf2f(short s) {
    return __uint_as_float(((unsigned)(unsigned short)s) << 16);
}

// ===========================================================================
// fp32 tiled GEMM (z_a producer — decision-grade accuracy — and fallback)
// ===========================================================================
#define TILE 64
#define BK   32

template <int MODE>
__global__ __launch_bounds__(256) void gemm_f32(
    const float* __restrict__ A, const float* __restrict__ B,
    const float* __restrict__ bias, const float* __restrict__ aux,
    float* __restrict__ C, int M, int N, int K)
{
    __shared__ float As[BK][TILE + 4];
    __shared__ float Bs[BK][TILE];

    const int tid = threadIdx.x;
    const int tx = tid & 15;
    const int ty = tid >> 4;
    const int n0 = blockIdx.x * TILE;
    const int m0 = blockIdx.y * TILE;

    float acc[4][4] = {};

    for (int k0 = 0; k0 < K; k0 += BK) {
        #pragma unroll
        for (int it = 0; it < 2; ++it) {
            int lin = tid + it * 256;
            int row = lin >> 3;
            int c4  = lin & 7;
            float4 a = *(const float4*)&A[(size_t)(m0 + row) * K + k0 + c4 * 4];
            As[c4 * 4 + 0][row] = a.x;
            As[c4 * 4 + 1][row] = a.y;
            As[c4 * 4 + 2][row] = a.z;
            As[c4 * 4 + 3][row] = a.w;
        }
        #pragma unroll
        for (int it = 0; it < 2; ++it) {
            int lin = tid + it * 256;
            int row = lin >> 4;
            int c4  = lin & 15;
            *(float4*)&Bs[row][c4 * 4] =
                *(const float4*)&B[(size_t)(k0 + row) * N + n0 + c4 * 4];
        }
        __syncthreads();

        #pragma unroll
        for (int k = 0; k < BK; ++k) {
            float4 av = *(const float4*)&As[k][ty * 4];
            float4 bv = *(const float4*)&Bs[k][tx * 4];
            float a_[4] = {av.x, av.y, av.z, av.w};
            float b_[4] = {bv.x, bv.y, bv.z, bv.w};
            #pragma unroll
            for (int i = 0; i < 4; ++i)
                #pragma unroll
                for (int j = 0; j < 4; ++j)
                    acc[i][j] = fmaf(a_[i], b_[j], acc[i][j]);
        }
        __syncthreads();
    }

    #pragma unroll
    for (int i = 0; i < 4; ++i) {
        int m = m0 + ty * 4 + i;
        int n = n0 + tx * 4;
        float4 out;
        float* o = (float*)&out;
        #pragma unroll
        for (int j = 0; j < 4; ++j) {
            float v = acc[i][j] + bias[n + j];
            if (MODE == 1) v = aux[(size_t)m * MG + ((n + j) >> 3)] + v;
            o[j] = v;
        }
        *(float4*)&C[(size_t)m * N + n] = out;
    }
}

__global__ __launch_bounds__(256) void block_min(
    const float* __restrict__ x, int n, float* __restrict__ out)
{
    __shared__ float red[256];
    float v = 3.402823466e+38f;
    for (int i = blockIdx.x * 256 + threadIdx.x; i < n; i += gridDim.x * 256)
        v = fminf(v, x[i]);
    red[threadIdx.x] = v;
    __syncthreads();
    for (int s = 128; s > 0; s >>= 1) {
        if (threadIdx.x < s)
            red[threadIdx.x] = fminf(red[threadIdx.x], red[threadIdx.x + s]);
        __syncthreads();
    }
    if (threadIdx.x == 0) out[blockIdx.x] = red[0];
}

__global__ __launch_bounds__(256) void row_kernel(
    const float* __restrict__ sigma, const float* __restrict__ phi,
    const float* __restrict__ psi, const float* __restrict__ minval,
    float* __restrict__ decode, float* __restrict__ xb_new,
    float* __restrict__ phi_new, float* __restrict__ psi_new)
{
    __shared__ unsigned long long keys[MG];
    __shared__ int acell[MG];
    __shared__ int win[MG];

    const int b = blockIdx.x;
    const int tid = threadIdx.x;
    const float smin = minval[0];
    const float* srow = sigma + (size_t)b * TOTAL;
    const float* prow = phi + (size_t)b * TOTAL;
    const float* qrow = psi + (size_t)b * TOTAL;

    for (int g = tid; g < MG; g += 256) {
        float best = -3.402823466e+38f;
        int bc = 0;
        #pragma unroll
        for (int c = 0; c < NC; ++c) {
            float s = srow[g * NC + c];
            float p = prow[g * NC + c];
            float pi = (1.0f - p) * ((s - smin) + 1.0f);
            if (pi > best) { best = pi; bc = c; }
        }
        unsigned int bits = __float_as_uint(best);
        unsigned int u = (bits & 0x80000000u) ? ~bits : (bits | 0x80000000u);
        keys[g] = ((unsigned long long)(~u) << 32) | (unsigned int)g;
        acell[g] = bc;
        win[g] = 0;
    }
    __syncthreads();

    for (int k = 2; k <= MG; k <<= 1) {
        for (int j = k >> 1; j > 0; j >>= 1) {
            for (int t = tid; t < MG; t += 256) {
                int ixj = t ^ j;
                if (ixj > t) {
                    unsigned long long a = keys[t], bb_ = keys[ixj];
                    bool asc = ((t & k) == 0);
                    if ((a > bb_) == asc) { keys[t] = bb_; keys[ixj] = a; }
                }
            }
            __syncthreads();
        }
    }
    if (tid < KGRP) {
        int g = (int)(keys[tid] & 0xFFFFFFFFu);
        win[g] = 1;
    }
    __syncthreads();

    for (int j = tid; j < TOTAL; j += 256) {
        int g = j >> 3, c = j & 7;
        float s = srow[j];
        float y = 0.0f;
        if (win[g] && acell[g] == c) y = tanhf(s);
        float pn = fmaxf(prow[j] * 0.5f, y);
        float qn = fmaxf(qrow[j] * 0.5f, y);
        phi_new[(size_t)b * TOTAL + j] = pn;
        psi_new[(size_t)b * TOTAL + j] = qn;
        xb_new[(size_t)b * TOTAL + j] = qn;
    }

    for (int g = tid; g < MG; g += 256) {
        float d = 0.0f;
        if (win[g]) d = fmaxf(0.0f, tanhf(srow[g * NC + acell[g]]));
        decode[(size_t)b * MG + g] = d;
    }
}

// ===========================================================================
// bf16x3 MFMA GEMM: part[kslice] = A[m-tile, kslice] @ B[kslice, n-tile]
// BM=128, BN=256, BK=64. 512 threads = 8 waves (4 wave-rows x 2 wave-cols),
// wave tile 32x128, acc[2][8]. A-frags direct global->VGPR. B dbuf in LDS,
// reg-staged issue-early/write-late. KEY (r8): raw s_barrier + lgkmcnt(0)
// only — the B prefetch loads stay IN FLIGHT across the barrier (T4);
// __syncthreads would drain vmcnt(0) and serialize the HBM round-trip.
// ===========================================================================
__global__ __launch_bounds__(256) void convert_bf(
    const float* __restrict__ src, short* __restrict__ h, short* __restrict__ l,
    int nchunks)
{
    for (int t = blockIdx.x * 256 + threadIdx.x; t < nchunks; t += gridDim.x * 256) {
        size_t idx = (size_t)t * 8;
        float4 v0 = *(const float4*)&src[idx];
        float4 v1 = *(const float4*)&src[idx + 4];
        float vv[8] = {v0.x, v0.y, v0.z, v0.w, v1.x, v1.y, v1.z, v1.w};
        bf16x8 hv, lv;
        #pragma unroll
        for (int e = 0; e < 8; ++e) {
            short hh = f2bf(vv[e]);
            hv[e] = hh;
            lv[e] = f2bf(vv[e] - bf2f(hh));
        }
        *(bf16x8*)&h[idx] = hv;
        *(bf16x8*)&l[idx] = lv;
    }
}

template <int KD, int BSTRIDE, int KPER>
__global__ __launch_bounds__(512, 2) void gemm_mfma(
    const short* __restrict__ Ah_g, const short* __restrict__ Al_g,
    const float* __restrict__ Bg, float* __restrict__ part)
{
    // [buf][n][8 chunks of 8k], chunk pos = kc ^ (n&7)  (proven r3 swizzle)
    __shared__ short Bh[2][256 * 64];   // 64 KB
    __shared__ short Bl[2][256 * 64];   // 64 KB

    const int tid = threadIdx.x;
    const int l = tid & 63;
    const int w = tid >> 6;
    const int wr = w >> 1;              // wave row (0..3), 32 rows each
    const int wc = w & 1;               // wave col (0..1), 128 cols each
    const int n0 = blockIdx.x * 256;
    const int m0 = blockIdx.y * 128;
    const int k0 = blockIdx.z * KPER;
    constexpr int NSTEP = KPER / 64;

    const int kc = tid & 7;             // B-stage k-chunk (spreads write banks)
    const int n4 = (tid >> 3) * 4;      // B-stage n quad (0..252)

    f32x4 acc[2][8] = {};
    float4 f[8];

    // prologue: issue step-0 B-tile loads
    #pragma unroll
    for (int it = 0; it < 8; ++it)
        f[it] = *(const float4*)&Bg[(size_t)(k0 + kc * 8 + it) * BSTRIDE + n0 + n4];

    for (int st = 0; st < NSTEP; ++st) {
        const int cur = st & 1;
        const int kw = k0 + st * 64;

        // write staged regs -> LDS buf[cur] (convert fp32 -> hi/lo)
        // (compiler auto-inserts the vmcnt wait for f here)
        #pragma unroll
        for (int j = 0; j < 4; ++j) {
            bf16x8 hv, lv;
            #pragma unroll
            for (int it = 0; it < 8; ++it) {
                float v = ((const float*)&f[it])[j];
                short hh = f2bf(v);
                hv[it] = hh;
                lv[it] = f2bf(v - bf2f(hh));
            }
            int n = n4 + j;
            int off = n * 64 + ((kc ^ (n & 7)) * 8);
            *(bf16x8*)&Bh[cur][off] = hv;
            *(bf16x8*)&Bl[cur][off] = lv;
        }
        // issue next-step loads early; they stay in flight ACROSS the barrier
        if (st + 1 < NSTEP) {
            const int kn = kw + 64;
            #pragma unroll
            for (int it = 0; it < 8; ++it)
                f[it] = *(const float4*)&Bg[(size_t)(kn + kc * 8 + it) * BSTRIDE + n0 + n4];
        }
        // LDS writes visible to the block, but do NOT drain vmcnt:
        // raw barrier instead of __syncthreads (which would wait vmcnt(0)).
        asm volatile("s_waitcnt lgkmcnt(0)" ::: "memory");
        __builtin_amdgcn_sched_barrier(0);
        __builtin_amdgcn_s_barrier();
        __builtin_amdgcn_sched_barrier(0);

        // compute: A-frags direct from global planes; B-frags from LDS
        #pragma unroll
        for (int kk = 0; kk < 2; ++kk) {
            const int chunk = kk * 4 + (l >> 4);
            bf16x8 ah[2], al[2];
            #pragma unroll
            for (int mt = 0; mt < 2; ++mt) {
                int row = m0 + wr * 32 + mt * 16 + (l & 15);
                size_t g = (size_t)row * KD + kw + chunk * 8;
                ah[mt] = *(const bf16x8*)&Ah_g[g];
                al[mt] = *(const bf16x8*)&Al_g[g];
            }
            #pragma unroll
            for (int nt = 0; nt < 8; ++nt) {
                int n = wc * 128 + nt * 16 + (l & 15);
                int off = n * 64 + ((chunk ^ (n & 7)) * 8);
                bf16x8 bh = *(const bf16x8*)&Bh[cur][off];
                bf16x8 bl = *(const bf16x8*)&Bl[cur][off];
                #pragma unroll
                for (int mt = 0; mt < 2; ++mt) {
                    acc[mt][nt] = __builtin_amdgcn_mfma_f32_16x16x32_bf16(
                        ah[mt], bh, acc[mt][nt], 0, 0, 0);
                    acc[mt][nt] = __builtin_amdgcn_mfma_f32_16x16x32_bf16(
                        ah[mt], bl, acc[mt][nt], 0, 0, 0);
                    acc[mt][nt] = __builtin_amdgcn_mfma_f32_16x16x32_bf16(
                        al[mt], bh, acc[mt][nt], 0, 0, 0);
                }
            }
        }
        // no trailing barrier: next step writes the OTHER buffer, and a wave
        // can only be one barrier ahead of its siblings.
    }

    // Epilogue: D layout col = lane&15, row = (lane>>4)*4 + reg
    float* P = part + (size_t)blockIdx.z * BSZ * BSTRIDE;
    #pragma unroll
    for (int mt = 0; mt < 2; ++mt) {
        int m = m0 + wr * 32 + mt * 16 + (l >> 4) * 4;
        #pragma unroll
        for (int nt = 0; nt < 8; ++nt) {
            int n = n0 + wc * 128 + nt * 16 + (l & 15);
            #pragma unroll
            for (int r = 0; r < 4; ++r)
                P[(size_t)(m + r) * BSTRIDE + n] = acc[mt][nt][r];
        }
    }
}

// Partial reduce + bias (+ z_a repeat + global-min for MODE 1).
// `out` may alias part slice 0 (element-wise read-then-write) -> no __restrict__.
template <int NSL, int NDIM, int MODE, int STR4>
__global__ __launch_bounds__(256) void reduce_part(
    const float* part, const float* __restrict__ aux,
    const float* __restrict__ bias, float* out,
    float* __restrict__ bmin)
{
    __shared__ float red[256];
    int i = blockIdx.x * 256 + threadIdx.x;
    size_t b4 = (size_t)i * 4;
    float4 s = {0.f, 0.f, 0.f, 0.f};
    #pragma unroll
    for (int sl = 0; sl < NSL; ++sl) {
        float4 p = *(const float4*)&part[(size_t)sl * STR4 * 4 + b4];
        s.x += p.x; s.y += p.y; s.z += p.z; s.w += p.w;
    }
    int col = (int)(b4 & (NDIM - 1));
    float4 bv = *(const float4*)&bias[col];
    float az = 0.f;
    if (MODE == 1) {
        int m = (int)(b4 >> 13);
        az = aux[m * MG + (col >> 3)];
    }
    s.x += bv.x + az; s.y += bv.y + az; s.z += bv.z + az; s.w += bv.w + az;
    *(float4*)&out[b4] = s;

    if (MODE == 1) {
        float v = fminf(fminf(s.x, s.y), fminf(s.z, s.w));
        red[threadIdx.x] = v;
        __syncthreads();
        for (int st = 128; st > 0; st >>= 1) {
            if (threadIdx.x < st)
                red[threadIdx.x] = fminf(red[threadIdx.x], red[threadIdx.x + st]);
            __syncthreads();
        }
        if (threadIdx.x == 0) bmin[blockIdx.x] = red[0];
    }
}

// ---------------------------------------------------------------------------
extern "C" void kernel_launch(void* const* d_in, const int* in_sizes, int n_in,
                              void* d_out, int out_size, void* d_ws, size_t ws_size,
                              hipStream_t stream)
{
    const float* x_a = (const float*)d_in[0];
    const float* x_b = (const float*)d_in[1];
    const float* phi = (const float*)d_in[2];
    const float* psi = (const float*)d_in[3];
    const float* Wa  = (const float*)d_in[4];
    const float* ba  = (const float*)d_in[5];
    const float* Wb  = (const float*)d_in[6];
    const float* bb  = (const float*)d_in[7];
    const float* Wd  = (const float*)d_in[8];
    const float* bd  = (const float*)d_in[9];

    float* out = (float*)d_out;
    float* pred    = out;
    float* xb_new  = out + BSZ * D_OUT;
    float* phi_new = out + BSZ * D_OUT + BSZ * TOTAL;
    float* psi_new = out + BSZ * D_OUT + 2 * BSZ * TOTAL;

    float* ws = (float*)d_ws;
    dim3 blk(256);
    dim3 blk512(512);

    // Workspace layout (float offsets); all 16B-aligned.
    // sigma ALIASES part slice 0 (see reduce_part note).
    const size_t OFF_ZA     = 0;            // 262144
    const size_t OFF_DECODE = 262144;       // 262144
    const size_t OFF_BMIN   = 524288;       // 2048
    const size_t OFF_MINV   = 526336;       // 16
    const size_t OFF_XBH    = 526352;       // 1048576 (2M shorts)
    const size_t OFF_XBL    = 1574928;      // 1048576
    const size_t OFF_DECH   = 2623504;      // 131072 (256K shorts)
    const size_t OFF_DECL   = 2754576;      // 131072
    const size_t OFF_PART   = 2885648;      // 8388608 floats (32 MB)
    const size_t NEED = (OFF_PART + 8388608) * 4;    // ~45.1 MB (proven fits)

    if (ws_size >= NEED) {
        float* z_a    = ws + OFF_ZA;
        float* decode = ws + OFF_DECODE;
        float* bmin   = ws + OFF_BMIN;
        float* minv   = ws + OFF_MINV;
        short* xbh    = (short*)(ws + OFF_XBH);
        short* xbl    = (short*)(ws + OFF_XBL);
        short* dech   = (short*)(ws + OFF_DECH);
        short* decl   = (short*)(ws + OFF_DECL);
        float* part   = ws + OFF_PART;
        float* sigma  = part;                 // alias, slice 0

        // z_a = x_a @ Wa + ba  -- fp32 (decision-grade accuracy; feeds top-k)
        gemm_f32<0><<<dim3(MG / TILE, BSZ / TILE), blk, 0, stream>>>(
            x_a, Wa, ba, nullptr, z_a, BSZ, MG, D_IN);

        // sigma = repeat(z_a,8) + x_b @ Wb + bb  -- bf16x3 MFMA
        convert_bf<<<1024, blk, 0, stream>>>(x_b, xbh, xbl, BSZ * TOTAL / 8);
        gemm_mfma<TOTAL, TOTAL, 2048><<<dim3(TOTAL / 256, 2, 4), blk512, 0, stream>>>(
            xbh, xbl, Wb, part);
        reduce_part<4, TOTAL, 1, 524288><<<2048, blk, 0, stream>>>(
            part, z_a, bb, sigma, bmin);
        block_min<<<1, blk, 0, stream>>>(bmin, 2048, minv);

        // masks, y, elementwise outputs, decode_in (consumes sigma)
        row_kernel<<<BSZ, blk, 0, stream>>>(
            sigma, phi, psi, minv, decode, xb_new, phi_new, psi_new);

        // pred = decode @ Wd + bd  -- bf16x3 MFMA (no decisions downstream)
        convert_bf<<<128, blk, 0, stream>>>(decode, dech, decl, BSZ * MG / 8);
        gemm_mfma<MG, D_OUT, 64><<<dim3(D_OUT / 256, 2, 16), blk512, 0, stream>>>(
            dech, decl, Wd, part);
        reduce_part<16, D_OUT, 2, 131072><<<512, blk, 0, stream>>>(
            part, nullptr, bd, pred, nullptr);
    } else {
        // Fallback: proven fp32 path (needs ~10.5 MB ws)
        float* z_a    = ws;
        float* sigma  = ws + 262144;
        float* decode = ws + 262144 + 2097152;
        float* bmin   = ws + 2621440;
        float* minv   = ws + 2622464;

        gemm_f32<0><<<dim3(MG / TILE, BSZ / TILE), blk, 0, stream>>>(
            x_a, Wa, ba, nullptr, z_a, BSZ, MG, D_IN);
        gemm_f32<1><<<dim3(TOTAL / TILE, BSZ / TILE), blk, 0, stream>>>(
            x_b, Wb, bb, z_a, sigma, BSZ, TOTAL, TOTAL);
        block_min<<<1024, blk, 0, stream>>>(sigma, BSZ * TOTAL, bmin);
        block_min<<<1, blk, 0, stream>>>(bmin, 1024, minv);
        row_kernel<<<BSZ, blk, 0, stream>>>(
            sigma, phi, psi, minv, decode, xb_new, phi_new, psi_new);
        gemm_f32<0><<<dim3(D_OUT / TILE, BSZ / TILE), blk, 0, stream>>>(
            decode, Wd, bd, nullptr, pred, BSZ, D_OUT, MG);
    }
}